// Round 15
// baseline (377.977 us; speedup 1.0000x reference)
//
#include <hip/hip_runtime.h>
#include <math.h>

#define N_NODES 50000
#define E_TRAIN 800000
#define E_POS 200000
#define E_NEG 200000

// ---------------- degree / CSR build ----------------

__global__ void count_kernel(const int* __restrict__ dst, int* __restrict__ cnt, int e) {
    int i = blockIdx.x * blockDim.x + threadIdx.x;
    if (i < e) atomicAdd(&cnt[dst[i]], 1);
}

// scan1 + dis fused: block-level exclusive scan of cnt, plus dis = rsqrt(deg+1)
__global__ void scan1_kernel(const int* __restrict__ cnt, int* __restrict__ offs,
                             int* __restrict__ bsum, float* __restrict__ dis, int n) {
    __shared__ int s[256];
    int i = blockIdx.x * 256 + threadIdx.x;
    int c = (i < n) ? cnt[i] : 0;
    if (i < n) dis[i] = 1.0f / sqrtf((float)(c + 1));  // +1 self loop
    s[threadIdx.x] = c;
    __syncthreads();
    for (int d = 1; d < 256; d <<= 1) {
        int t = 0;
        if ((int)threadIdx.x >= d) t = s[threadIdx.x - d];
        __syncthreads();
        if ((int)threadIdx.x >= d) s[threadIdx.x] += t;
        __syncthreads();
    }
    if (i < n) offs[i] = s[threadIdx.x] - c;  // exclusive
    if (threadIdx.x == 255) bsum[blockIdx.x] = s[255];
}

// scan3 with scan2 folded in: every block scans the 196 block sums in LDS
// (redundant but trivial), then applies its prefix. Saves one kernel launch.
__global__ void scan3_kernel(int* __restrict__ offs, const int* __restrict__ bsum,
                             int* __restrict__ cursor, int n, int nb) {
    __shared__ int s[256];
    int t = threadIdx.x;
    int v = (t < nb) ? bsum[t] : 0;
    s[t] = v;
    __syncthreads();
    for (int d = 1; d < 256; d <<= 1) {
        int u = 0;
        if (t >= d) u = s[t - d];
        __syncthreads();
        if (t >= d) s[t] += u;
        __syncthreads();
    }
    // s[t] is inclusive scan; exclusive prefix of block b = s[b] - bsum[b]
    int i = blockIdx.x * 256 + t;
    if (i < n) {
        int b = i >> 8;
        int pre = s[b] - ((b < nb) ? bsum[b] : 0);
        int o = offs[i] + pre;
        offs[i] = o; cursor[i] = o;
    }
}

// csr entries are ushort: src node ids < 50000 < 65536
__global__ void fill_kernel(const int* __restrict__ src, const int* __restrict__ dst,
                            int* __restrict__ cursor, unsigned short* __restrict__ csr_src, int e) {
    int i = blockIdx.x * blockDim.x + threadIdx.x;
    if (i < e) {
        int p = atomicAdd(&cursor[dst[i]], 1);
        csr_src[p] = (unsigned short)src[i];
    }
}

// ---------------- bf16 helpers ----------------

__device__ inline void split_bf16(float f, short& h, short& l) {
    unsigned u = __float_as_uint(f);
    h = (short)(u >> 16);
    float rem = f - __uint_as_float(u & 0xFFFF0000u);
    l = (short)(__float_as_uint(rem) >> 16);
}

__device__ inline unsigned short f2bf_rne(float f) {
    unsigned u = __float_as_uint(f);
    unsigned r = u + 0x7FFFu + ((u >> 16) & 1u);
    return (unsigned short)(r >> 16);
}

__device__ inline float bf2f(unsigned short h) {
    return __uint_as_float(((unsigned)h) << 16);
}

#define WTOT (128 * 256 + 256 * 128 + 128 * 64)

// weights -> transposed hi/lo bf16, PLUS x -> bf16 gather table, one launch
__global__ void prep_kernel(const float* __restrict__ W1, short* __restrict__ W1h, short* __restrict__ W1l,
                            const float* __restrict__ W2, short* __restrict__ W2h, short* __restrict__ W2l,
                            const float* __restrict__ W3, short* __restrict__ W3h, short* __restrict__ W3l,
                            const float* __restrict__ x, unsigned short* __restrict__ xb, int n4) {
    int i = blockIdx.x * blockDim.x + threadIdx.x;
    if (i < WTOT) {
        const float* W; short *Wh, *Wl; int K, N;
        if (i < 128 * 256) { W = W1; Wh = W1h; Wl = W1l; K = 128; N = 256; }
        else if (i < 128 * 256 + 256 * 128) { i -= 128 * 256; W = W2; Wh = W2h; Wl = W2l; K = 256; N = 128; }
        else { i -= 128 * 256 + 256 * 128; W = W3; Wh = W3h; Wl = W3l; K = 128; N = 64; }
        int k = i / N, n = i - k * N;
        short h, l;
        split_bf16(W[i], h, l);
        Wh[(size_t)n * K + k] = h;
        Wl[(size_t)n * K + k] = l;
    } else {
        int j = i - WTOT;
        if (j < n4) {
            float4 v = ((const float4*)x)[j];
            ushort4 o;
            o.x = f2bf_rne(v.x); o.y = f2bf_rne(v.y);
            o.z = f2bf_rne(v.z); o.w = f2bf_rne(v.w);
            ((ushort4*)xb)[j] = o;
        }
    }
}

// ---------------- MFMA GEMM: 512 threads, 128 rows x full N, A streamed, B in LDS ----------------
// (R11 structure, proven: 8 waves/block, register-prefetch, transpose epilogue.)
// OBF: emit C as bf16 RNE (ushort) for gather consumers; else fp32.

typedef short bf16x8 __attribute__((ext_vector_type(8)));
typedef float f32x4 __attribute__((ext_vector_type(4)));

template<int BN, bool BR, bool OBF>
__global__ __launch_bounds__(512) void gemm_fulln_kernel(
        const float* __restrict__ A,
        const short* __restrict__ Bth, const short* __restrict__ Btl,
        const float* __restrict__ bias, float* __restrict__ C,
        unsigned short* __restrict__ Cb,
        int M, int K) {
    constexpr int NI = BN / 16;              // 16x16 tiles per wave
    constexpr int BCH = BN * 4;              // int4 chunks per B array per k-tile
    constexpr int BP = (BCH + 511) / 512;    // chunks per thread
    constexpr size_t BSZ = (size_t)2 * BN * 40 * 2;   // hi+lo, stride 40 shorts
    constexpr size_t TSZ = (size_t)8 * 16 * 68 * 4;   // 8-wave transpose buffer
    __shared__ __align__(16) char smem[BSZ > TSZ ? BSZ : TSZ];
    short* Bhi = (short*)smem;
    short* Blo = (short*)(smem + (size_t)BN * 40 * 2);
    float* tr  = (float*)smem;               // aliased after final barrier

    int tid = threadIdx.x;
    int lane = tid & 63;
    int wv = tid >> 6;                       // 0..7
    int brow = blockIdx.x * 128;
    int m_lane = lane & 15;
    int kgrp = lane >> 4;                    // 0..3

    int myrow = brow + wv * 16 + m_lane;
    if (myrow >= M) myrow = M - 1;           // clamp; garbage rows discarded at store
    const float* Ap = &A[(size_t)myrow * K + kgrp * 8];

    f32x4 acc[NI];
    #pragma unroll
    for (int i = 0; i < NI; i++) acc[i] = (f32x4){0.f, 0.f, 0.f, 0.f};

    int4 bhReg[BP], blReg[BP];
    float4 aN0, aN1, aC0, aC1;

    auto loadB = [&](int k0) {
        #pragma unroll
        for (int p = 0; p < BP; p++) {
            int idx = p * 512 + tid;
            if (idx < BCH) {
                int col = idx >> 2;
                int kc = idx & 3;
                size_t o = (size_t)col * K + k0 + kc * 8;
                bhReg[p] = *(const int4*)&Bth[o];
                blReg[p] = *(const int4*)&Btl[o];
            }
        }
    };
    auto loadA = [&](int k0) {
        aN0 = *(const float4*)&Ap[k0];
        aN1 = *(const float4*)&Ap[k0 + 4];
    };

    loadB(0); loadA(0);

    for (int k0 = 0; k0 < K; k0 += 32) {
        aC0 = aN0; aC1 = aN1;
        #pragma unroll
        for (int p = 0; p < BP; p++) {
            int idx = p * 512 + tid;
            if (idx < BCH) {
                int col = idx >> 2;
                int kc = idx & 3;
                *(int4*)&Bhi[col * 40 + kc * 8] = bhReg[p];
                *(int4*)&Blo[col * 40 + kc * 8] = blReg[p];
            }
        }
        __syncthreads();

        if (k0 + 32 < K) { loadB(k0 + 32); loadA(k0 + 32); }  // overlaps MFMA phase

        bf16x8 ah, al;
        {
            short h, l;
            split_bf16(aC0.x, h, l); ah[0] = h; al[0] = l;
            split_bf16(aC0.y, h, l); ah[1] = h; al[1] = l;
            split_bf16(aC0.z, h, l); ah[2] = h; al[2] = l;
            split_bf16(aC0.w, h, l); ah[3] = h; al[3] = l;
            split_bf16(aC1.x, h, l); ah[4] = h; al[4] = l;
            split_bf16(aC1.y, h, l); ah[5] = h; al[5] = l;
            split_bf16(aC1.z, h, l); ah[6] = h; al[6] = l;
            split_bf16(aC1.w, h, l); ah[7] = h; al[7] = l;
        }
        #pragma unroll
        for (int ni = 0; ni < NI; ni++) {
            int boff = (ni * 16 + m_lane) * 40 + kgrp * 8;
            bf16x8 bh = *(const bf16x8*)&Bhi[boff];
            bf16x8 bl = *(const bf16x8*)&Blo[boff];
            acc[ni] = __builtin_amdgcn_mfma_f32_16x16x32_bf16(ah, bh, acc[ni], 0, 0, 0);
            acc[ni] = __builtin_amdgcn_mfma_f32_16x16x32_bf16(al, bh, acc[ni], 0, 0, 0);
            acc[ni] = __builtin_amdgcn_mfma_f32_16x16x32_bf16(ah, bl, acc[ni], 0, 0, 0);
        }
        __syncthreads();
    }

    // epilogue: acc col = ni*16 + m_lane, local row = kgrp*4 + reg.
    // Chunks of 4 ni (64 cols): wave-local LDS transpose, then coalesced stores.
    #pragma unroll
    for (int c = 0; c < NI / 4; c++) {
        #pragma unroll
        for (int q = 0; q < 4; q++) {
            int ni = c * 4 + q;
            float bb = 0.f;
            if (BR) bb = bias[ni * 16 + m_lane];
            #pragma unroll
            for (int reg = 0; reg < 4; reg++) {
                float v = acc[ni][reg];
                if (BR) v = fmaxf(v + bb, 0.f);
                tr[wv * 1088 + (kgrp * 4 + reg) * 68 + q * 16 + m_lane] = v;
            }
        }
        // same-wave LDS RAW: in-order DS pipe + compiler lgkmcnt; no barrier needed
        #pragma unroll
        for (int j = 0; j < 4; j++) {
            int r = (lane >> 4) + j * 4;
            int g = lane & 15;
            float4 v = *(const float4*)&tr[wv * 1088 + r * 68 + g * 4];
            int row = brow + wv * 16 + r;
            if (row < M) {
                if (OBF) {
                    ushort4 o;
                    o.x = f2bf_rne(v.x); o.y = f2bf_rne(v.y);
                    o.z = f2bf_rne(v.z); o.w = f2bf_rne(v.w);
                    *(ushort4*)&Cb[(size_t)row * BN + c * 64 + g * 4] = o;
                } else {
                    *(float4*)&C[(size_t)row * BN + c * 64 + g * 4] = v;
                }
            }
        }
    }
}

// ---------------- aggregation over bf16 gather table (ushort csr) ----------------
// Persistent waves: fixed grid, each wave strides over ~4 nodes (load balance,
// longer wave lifetime, less scheduling churn). 16-edge batch ILP inside.

#define AGG_WAVES 12800
#define AGG_BLOCKS (AGG_WAVES / 4)

template<int F, bool RELU, bool BIAS>
__global__ void aggregate_bf16_kernel(const unsigned short* __restrict__ xb,
                                      float* __restrict__ out,
                                      const float* __restrict__ dis,
                                      const int* __restrict__ starts,
                                      const int* __restrict__ ends,
                                      const unsigned short* __restrict__ csr_src,
                                      const float* __restrict__ bias,
                                      int n) {
    int wid = (blockIdx.x * blockDim.x + threadIdx.x) >> 6;
    int lane = threadIdx.x & 63;
    constexpr int VPT = F / 64;

    for (int v = wid; v < n; v += AGG_WAVES) {
        float dv = dis[v];
        float acc[VPT];
        if constexpr (VPT == 2) {
            ushort2 sv = *(const ushort2*)&xb[(size_t)v * F + lane * 2];
            acc[0] = bf2f(sv.x) * dv * dv;
            acc[1] = bf2f(sv.y) * dv * dv;
        } else {
            acc[0] = bf2f(xb[(size_t)v * F + lane]) * dv * dv;
        }
        int s = starts[v], e = ends[v];
        int p = s;
        for (; p + 16 <= e; p += 16) {
            int u[16];
            #pragma unroll
            for (int q = 0; q < 16; q++) u[q] = csr_src[p + q];
            float w[16];
            #pragma unroll
            for (int q = 0; q < 16; q++) w[q] = dis[u[q]] * dv;
            if constexpr (VPT == 2) {
                ushort2 g[16];
                #pragma unroll
                for (int q = 0; q < 16; q++)
                    g[q] = *(const ushort2*)&xb[(size_t)u[q] * F + lane * 2];
                #pragma unroll
                for (int q = 0; q < 16; q++) {
                    acc[0] += bf2f(g[q].x) * w[q];
                    acc[1] += bf2f(g[q].y) * w[q];
                }
            } else {
                unsigned short g[16];
                #pragma unroll
                for (int q = 0; q < 16; q++)
                    g[q] = xb[(size_t)u[q] * F + lane];
                #pragma unroll
                for (int q = 0; q < 16; q++) acc[0] += bf2f(g[q]) * w[q];
            }
        }
        for (; p + 8 <= e; p += 8) {
            int u[8];
            #pragma unroll
            for (int q = 0; q < 8; q++) u[q] = csr_src[p + q];
            float w[8];
            #pragma unroll
            for (int q = 0; q < 8; q++) w[q] = dis[u[q]] * dv;
            if constexpr (VPT == 2) {
                ushort2 g[8];
                #pragma unroll
                for (int q = 0; q < 8; q++)
                    g[q] = *(const ushort2*)&xb[(size_t)u[q] * F + lane * 2];
                #pragma unroll
                for (int q = 0; q < 8; q++) {
                    acc[0] += bf2f(g[q].x) * w[q];
                    acc[1] += bf2f(g[q].y) * w[q];
                }
            } else {
                unsigned short g[8];
                #pragma unroll
                for (int q = 0; q < 8; q++)
                    g[q] = xb[(size_t)u[q] * F + lane];
                #pragma unroll
                for (int q = 0; q < 8; q++) acc[0] += bf2f(g[q]) * w[q];
            }
        }
        for (; p < e; p++) {
            int u = csr_src[p];
            float w = dis[u] * dv;
            if constexpr (VPT == 2) {
                ushort2 g = *(const ushort2*)&xb[(size_t)u * F + lane * 2];
                acc[0] += bf2f(g.x) * w;
                acc[1] += bf2f(g.y) * w;
            } else {
                acc[0] += bf2f(xb[(size_t)u * F + lane]) * w;
            }
        }
        float* o = &out[(size_t)v * F + lane * VPT];
        #pragma unroll
        for (int i = 0; i < VPT; i++) {
            float r = acc[i];
            if (BIAS) r += bias[lane * VPT + i];
            if (RELU) r = fmaxf(r, 0.f);
            o[i] = r;
        }
    }
}

// ---------------- edge dot products: 16 lanes per edge, 4 edges per wave ----------------

__global__ void dot_kernel(const float* __restrict__ h,
                           const int* __restrict__ pos, const int* __restrict__ neg,
                           float* __restrict__ out) {
    int gw = (blockIdx.x * blockDim.x + threadIdx.x) >> 6;
    int lane = threadIdx.x & 63;
    int sub = lane >> 4;          // edge within wave (0..3)
    int pl = lane & 15;           // float4 position within row
    int e = gw * 4 + sub;
    if (e >= E_POS + E_NEG) return;
    int i0, i1;
    if (e < E_POS) { i0 = pos[e]; i1 = pos[E_POS + e]; }
    else { int t = e - E_POS; i0 = neg[t]; i1 = neg[E_NEG + t]; }
    float4 a = *(const float4*)&h[(size_t)i0 * 64 + pl * 4];
    float4 b = *(const float4*)&h[(size_t)i1 * 64 + pl * 4];
    float v = a.x * b.x + a.y * b.y + a.z * b.z + a.w * b.w;
    v += __shfl_xor(v, 1, 64);
    v += __shfl_xor(v, 2, 64);
    v += __shfl_xor(v, 4, 64);
    v += __shfl_xor(v, 8, 64);
    if (pl == 0) out[e] = v;
}

// ---------------- launch ----------------

extern "C" void kernel_launch(void* const* d_in, const int* in_sizes, int n_in,
                              void* d_out, int out_size, void* d_ws, size_t ws_size,
                              hipStream_t stream) {
    const float* x  = (const float*)d_in[0];
    const int* tei  = (const int*)d_in[1];
    const int* pos  = (const int*)d_in[2];
    const int* neg  = (const int*)d_in[3];
    const float* W1 = (const float*)d_in[4];
    const float* b1 = (const float*)d_in[5];
    const float* W2 = (const float*)d_in[6];
    const float* b2 = (const float*)d_in[7];
    const float* W3 = (const float*)d_in[8];
    const float* b3 = (const float*)d_in[9];
    float* out = (float*)d_out;

    const int* src = tei;
    const int* dst = tei + E_TRAIN;

    char* ws = (char*)d_ws;
    size_t off = 0;
    auto alloc = [&](size_t bytes) -> void* {
        void* p = ws + off;
        off = (off + bytes + 255) & ~(size_t)255;
        return p;
    };
    unsigned short* xb   = (unsigned short*)alloc((size_t)N_NODES * 128 * 2);  // x bf16
    float* aggX          = (float*)alloc((size_t)N_NODES * 128 * 4);
    float* h1            = (float*)alloc((size_t)N_NODES * 256 * 4);
    unsigned short* xw2b = (unsigned short*)alloc((size_t)N_NODES * 128 * 2);
    float* h2            = (float*)alloc((size_t)N_NODES * 128 * 4);
    unsigned short* xw3b = (unsigned short*)alloc((size_t)N_NODES * 64 * 2);
    float* h3            = (float*)alloc((size_t)N_NODES * 64 * 4);
    float* dis  = (float*)alloc(N_NODES * 4);
    int* cnt    = (int*)alloc(N_NODES * 4);
    int* offs   = (int*)alloc(N_NODES * 4);
    int* cursor = (int*)alloc(N_NODES * 4);
    int* bsum   = (int*)alloc(256 * 4);
    unsigned short* csr = (unsigned short*)alloc((size_t)E_TRAIN * 2);
    short* Wt1h = (short*)alloc((size_t)128 * 256 * 2);
    short* Wt1l = (short*)alloc((size_t)128 * 256 * 2);
    short* Wt2h = (short*)alloc((size_t)256 * 128 * 2);
    short* Wt2l = (short*)alloc((size_t)256 * 128 * 2);
    short* Wt3h = (short*)alloc((size_t)128 * 64 * 2);
    short* Wt3l = (short*)alloc((size_t)128 * 64 * 2);
    (void)ws_size; (void)n_in; (void)in_sizes; (void)out_size;

    hipMemsetAsync(cnt, 0, N_NODES * 4, stream);
    count_kernel<<<(E_TRAIN + 255) / 256, 256, 0, stream>>>(dst, cnt, E_TRAIN);
    int nb = (N_NODES + 255) / 256;  // 196
    scan1_kernel<<<nb, 256, 0, stream>>>(cnt, offs, bsum, dis, N_NODES);
    scan3_kernel<<<nb, 256, 0, stream>>>(offs, bsum, cursor, N_NODES, nb);
    fill_kernel<<<(E_TRAIN + 255) / 256, 256, 0, stream>>>(src, dst, cursor, csr, E_TRAIN);
    // after fill: offs[v] = start, cursor[v] = end

    const int n4 = N_NODES * 128 / 4;
    prep_kernel<<<(WTOT + n4 + 255) / 256, 256, 0, stream>>>(
        W1, Wt1h, Wt1l, W2, Wt2h, Wt2l, W3, Wt3h, Wt3l, x, xb, n4);

    const int GB = (N_NODES + 127) / 128;     // 391 blocks of 128 rows

    // layer 1 (agg-first): aggX = agg(xb) [F=128, fp32 out]; h1 = relu(aggX @ W1 + b1) [256 fp32]
    aggregate_bf16_kernel<128, false, false><<<AGG_BLOCKS, 256, 0, stream>>>(
        xb, aggX, dis, offs, cursor, csr, nullptr, N_NODES);
    gemm_fulln_kernel<256, true, false><<<GB, 512, 0, stream>>>(
        aggX, Wt1h, Wt1l, b1, h1, nullptr, N_NODES, 128);

    // layer 2 (gemm-first): xw2 = h1 @ W2 [128, bf16 out]; h2 = relu(agg(xw2b) + b2) [fp32]
    gemm_fulln_kernel<128, false, true><<<GB, 512, 0, stream>>>(
        h1, Wt2h, Wt2l, nullptr, nullptr, xw2b, N_NODES, 256);
    aggregate_bf16_kernel<128, true, true><<<AGG_BLOCKS, 256, 0, stream>>>(
        xw2b, h2, dis, offs, cursor, csr, b2, N_NODES);

    // layer 3 (gemm-first): xw3 = h2 @ W3 [64, bf16 out]; h3 = agg(xw3b) + b3 [fp32]
    gemm_fulln_kernel<64, false, true><<<GB, 512, 0, stream>>>(
        h2, Wt3h, Wt3l, nullptr, nullptr, xw3b, N_NODES, 128);
    aggregate_bf16_kernel<64, false, true><<<AGG_BLOCKS, 256, 0, stream>>>(
        xw3b, h3, dis, offs, cursor, csr, b3, N_NODES);

    // edge dots over h3 (64 features, fp32): 4 edges per wave
    const int DOT_WAVES = (E_POS + E_NEG + 3) / 4;            // 100000 waves
    dot_kernel<<<(DOT_WAVES + 3) / 4, 256, 0, stream>>>(h3, pos, neg, out);
}

// Round 16
// 330.519 us; speedup vs baseline: 1.1436x; 1.1436x over previous
//
#include <hip/hip_runtime.h>
#include <math.h>

#define N_NODES 50000
#define E_TRAIN 800000
#define E_POS 200000
#define E_NEG 200000

#define NBUCK 196        // ceil(N_NODES/256) coarse dst-buckets
#define BSTRIDE 5120     // temp slots per bucket (mean 4082, 16 sigma margin)

// ---------------- bf16 helpers ----------------

__device__ inline void split_bf16(float f, short& h, short& l) {
    unsigned u = __float_as_uint(f);
    h = (short)(u >> 16);
    float rem = f - __uint_as_float(u & 0xFFFF0000u);
    l = (short)(__float_as_uint(rem) >> 16);
}

__device__ inline unsigned short f2bf_rne(float f) {
    unsigned u = __float_as_uint(f);
    unsigned r = u + 0x7FFFu + ((u >> 16) & 1u);
    return (unsigned short)(r >> 16);
}

__device__ inline float bf2f(unsigned short h) {
    return __uint_as_float(((unsigned)h) << 16);
}

// ---------------- CSR build: 2-phase coarse radix partition ----------------
// Phase A: partition edges into NBUCK coarse buckets by dst>>8. Per-block LDS
// histogram + one global atomicAdd per (block,bucket) + contiguous-run writes
// of packed (src<<8 | dst&255) into fixed-stride temp.

__global__ void partA_kernel(const int* __restrict__ src, const int* __restrict__ dst,
                             int* __restrict__ gcount, unsigned int* __restrict__ temp, int e) {
    __shared__ int hist[NBUCK];
    __shared__ int base[NBUCK];
    __shared__ int lcur[NBUCK];
    int tid = threadIdx.x;
    for (int i = tid; i < NBUCK; i += 256) hist[i] = 0;
    __syncthreads();
    int start = blockIdx.x * 4096;
    int stop = min(start + 4096, e);
    for (int i = start + tid; i < stop; i += 256)
        atomicAdd(&hist[dst[i] >> 8], 1);
    __syncthreads();
    for (int i = tid; i < NBUCK; i += 256) {
        base[i] = atomicAdd(&gcount[i], hist[i]);
        lcur[i] = 0;
    }
    __syncthreads();
    for (int i = start + tid; i < stop; i += 256) {
        int d = dst[i];
        int b = d >> 8;
        int off = atomicAdd(&lcur[b], 1);
        temp[(size_t)b * BSTRIDE + base[b] + off] = ((unsigned)src[i] << 8) | (unsigned)(d & 255);
    }
}

// exclusive scan of the NBUCK bucket totals (single block)
__global__ void scanb_kernel(const int* __restrict__ gcount, int* __restrict__ gbase) {
    __shared__ int s[256];
    int t = threadIdx.x;
    int v = (t < NBUCK) ? gcount[t] : 0;
    s[t] = v;
    __syncthreads();
    for (int d = 1; d < 256; d <<= 1) {
        int u = 0;
        if (t >= d) u = s[t - d];
        __syncthreads();
        if (t >= d) s[t] += u;
        __syncthreads();
    }
    if (t < NBUCK) gbase[t] = s[t] - v;  // exclusive
}

// Phase B: one block per bucket (256 nodes). Per-node counts in LDS ->
// dis/offs/ends written directly (replaces count+scan kernels); then edges
// placed into csr via LDS cursors. All csr writes for a line come from this
// block -> no cross-XCD line bouncing.

__global__ void partB_kernel(const unsigned int* __restrict__ temp,
                             const int* __restrict__ gcount, const int* __restrict__ gbase,
                             float* __restrict__ dis, int* __restrict__ offs, int* __restrict__ ends,
                             unsigned short* __restrict__ csr) {
    __shared__ int cnt[256];
    __shared__ int loc[256];
    __shared__ int cursor[256];
    int b = blockIdx.x;
    int t = threadIdx.x;
    int total = gcount[b];
    size_t tbase = (size_t)b * BSTRIDE;
    cnt[t] = 0;
    __syncthreads();
    for (int i = t; i < total; i += 256)
        atomicAdd(&cnt[temp[tbase + i] & 255], 1);
    __syncthreads();
    int c = cnt[t];
    loc[t] = c;
    __syncthreads();
    for (int d = 1; d < 256; d <<= 1) {
        int u = 0;
        if (t >= d) u = loc[t - d];
        __syncthreads();
        if (t >= d) loc[t] += u;
        __syncthreads();
    }
    int excl = loc[t] - c;
    int node = b * 256 + t;
    int gstart = gbase[b] + excl;
    if (node < N_NODES) {
        dis[node] = 1.0f / sqrtf((float)(c + 1));  // +1 self loop
        offs[node] = gstart;
        ends[node] = gstart + c;
    }
    cursor[t] = gstart;
    __syncthreads();
    for (int i = t; i < total; i += 256) {
        unsigned v = temp[tbase + i];
        int pos = atomicAdd(&cursor[v & 255], 1);
        csr[pos] = (unsigned short)(v >> 8);
    }
}

#define WTOT (128 * 256 + 256 * 128 + 128 * 64)

// weights -> transposed hi/lo bf16, PLUS x -> bf16 gather table, one launch
__global__ void prep_kernel(const float* __restrict__ W1, short* __restrict__ W1h, short* __restrict__ W1l,
                            const float* __restrict__ W2, short* __restrict__ W2h, short* __restrict__ W2l,
                            const float* __restrict__ W3, short* __restrict__ W3h, short* __restrict__ W3l,
                            const float* __restrict__ x, unsigned short* __restrict__ xb, int n4) {
    int i = blockIdx.x * blockDim.x + threadIdx.x;
    if (i < WTOT) {
        const float* W; short *Wh, *Wl; int K, N;
        if (i < 128 * 256) { W = W1; Wh = W1h; Wl = W1l; K = 128; N = 256; }
        else if (i < 128 * 256 + 256 * 128) { i -= 128 * 256; W = W2; Wh = W2h; Wl = W2l; K = 256; N = 128; }
        else { i -= 128 * 256 + 256 * 128; W = W3; Wh = W3h; Wl = W3l; K = 128; N = 64; }
        int k = i / N, n = i - k * N;
        short h, l;
        split_bf16(W[i], h, l);
        Wh[(size_t)n * K + k] = h;
        Wl[(size_t)n * K + k] = l;
    } else {
        int j = i - WTOT;
        if (j < n4) {
            float4 v = ((const float4*)x)[j];
            ushort4 o;
            o.x = f2bf_rne(v.x); o.y = f2bf_rne(v.y);
            o.z = f2bf_rne(v.z); o.w = f2bf_rne(v.w);
            ((ushort4*)xb)[j] = o;
        }
    }
}

// ---------------- MFMA GEMM: 512 threads, 128 rows x full N, A streamed, B in LDS ----------------
// (R11 structure, proven: 8 waves/block, register-prefetch, transpose epilogue.)
// OBF: emit C as bf16 RNE (ushort) for gather consumers; else fp32.

typedef short bf16x8 __attribute__((ext_vector_type(8)));
typedef float f32x4 __attribute__((ext_vector_type(4)));

template<int BN, bool BR, bool OBF>
__global__ __launch_bounds__(512) void gemm_fulln_kernel(
        const float* __restrict__ A,
        const short* __restrict__ Bth, const short* __restrict__ Btl,
        const float* __restrict__ bias, float* __restrict__ C,
        unsigned short* __restrict__ Cb,
        int M, int K) {
    constexpr int NI = BN / 16;              // 16x16 tiles per wave
    constexpr int BCH = BN * 4;              // int4 chunks per B array per k-tile
    constexpr int BP = (BCH + 511) / 512;    // chunks per thread
    constexpr size_t BSZ = (size_t)2 * BN * 40 * 2;   // hi+lo, stride 40 shorts
    constexpr size_t TSZ = (size_t)8 * 16 * 68 * 4;   // 8-wave transpose buffer
    __shared__ __align__(16) char smem[BSZ > TSZ ? BSZ : TSZ];
    short* Bhi = (short*)smem;
    short* Blo = (short*)(smem + (size_t)BN * 40 * 2);
    float* tr  = (float*)smem;               // aliased after final barrier

    int tid = threadIdx.x;
    int lane = tid & 63;
    int wv = tid >> 6;                       // 0..7
    int brow = blockIdx.x * 128;
    int m_lane = lane & 15;
    int kgrp = lane >> 4;                    // 0..3

    int myrow = brow + wv * 16 + m_lane;
    if (myrow >= M) myrow = M - 1;           // clamp; garbage rows discarded at store
    const float* Ap = &A[(size_t)myrow * K + kgrp * 8];

    f32x4 acc[NI];
    #pragma unroll
    for (int i = 0; i < NI; i++) acc[i] = (f32x4){0.f, 0.f, 0.f, 0.f};

    int4 bhReg[BP], blReg[BP];
    float4 aN0, aN1, aC0, aC1;

    auto loadB = [&](int k0) {
        #pragma unroll
        for (int p = 0; p < BP; p++) {
            int idx = p * 512 + tid;
            if (idx < BCH) {
                int col = idx >> 2;
                int kc = idx & 3;
                size_t o = (size_t)col * K + k0 + kc * 8;
                bhReg[p] = *(const int4*)&Bth[o];
                blReg[p] = *(const int4*)&Btl[o];
            }
        }
    };
    auto loadA = [&](int k0) {
        aN0 = *(const float4*)&Ap[k0];
        aN1 = *(const float4*)&Ap[k0 + 4];
    };

    loadB(0); loadA(0);

    for (int k0 = 0; k0 < K; k0 += 32) {
        aC0 = aN0; aC1 = aN1;
        #pragma unroll
        for (int p = 0; p < BP; p++) {
            int idx = p * 512 + tid;
            if (idx < BCH) {
                int col = idx >> 2;
                int kc = idx & 3;
                *(int4*)&Bhi[col * 40 + kc * 8] = bhReg[p];
                *(int4*)&Blo[col * 40 + kc * 8] = blReg[p];
            }
        }
        __syncthreads();

        if (k0 + 32 < K) { loadB(k0 + 32); loadA(k0 + 32); }  // overlaps MFMA phase

        bf16x8 ah, al;
        {
            short h, l;
            split_bf16(aC0.x, h, l); ah[0] = h; al[0] = l;
            split_bf16(aC0.y, h, l); ah[1] = h; al[1] = l;
            split_bf16(aC0.z, h, l); ah[2] = h; al[2] = l;
            split_bf16(aC0.w, h, l); ah[3] = h; al[3] = l;
            split_bf16(aC1.x, h, l); ah[4] = h; al[4] = l;
            split_bf16(aC1.y, h, l); ah[5] = h; al[5] = l;
            split_bf16(aC1.z, h, l); ah[6] = h; al[6] = l;
            split_bf16(aC1.w, h, l); ah[7] = h; al[7] = l;
        }
        #pragma unroll
        for (int ni = 0; ni < NI; ni++) {
            int boff = (ni * 16 + m_lane) * 40 + kgrp * 8;
            bf16x8 bh = *(const bf16x8*)&Bhi[boff];
            bf16x8 bl = *(const bf16x8*)&Blo[boff];
            acc[ni] = __builtin_amdgcn_mfma_f32_16x16x32_bf16(ah, bh, acc[ni], 0, 0, 0);
            acc[ni] = __builtin_amdgcn_mfma_f32_16x16x32_bf16(al, bh, acc[ni], 0, 0, 0);
            acc[ni] = __builtin_amdgcn_mfma_f32_16x16x32_bf16(ah, bl, acc[ni], 0, 0, 0);
        }
        __syncthreads();
    }

    // epilogue: acc col = ni*16 + m_lane, local row = kgrp*4 + reg.
    // Chunks of 4 ni (64 cols): wave-local LDS transpose, then coalesced stores.
    #pragma unroll
    for (int c = 0; c < NI / 4; c++) {
        #pragma unroll
        for (int q = 0; q < 4; q++) {
            int ni = c * 4 + q;
            float bb = 0.f;
            if (BR) bb = bias[ni * 16 + m_lane];
            #pragma unroll
            for (int reg = 0; reg < 4; reg++) {
                float v = acc[ni][reg];
                if (BR) v = fmaxf(v + bb, 0.f);
                tr[wv * 1088 + (kgrp * 4 + reg) * 68 + q * 16 + m_lane] = v;
            }
        }
        // same-wave LDS RAW: in-order DS pipe + compiler lgkmcnt; no barrier needed
        #pragma unroll
        for (int j = 0; j < 4; j++) {
            int r = (lane >> 4) + j * 4;
            int g = lane & 15;
            float4 v = *(const float4*)&tr[wv * 1088 + r * 68 + g * 4];
            int row = brow + wv * 16 + r;
            if (row < M) {
                if (OBF) {
                    ushort4 o;
                    o.x = f2bf_rne(v.x); o.y = f2bf_rne(v.y);
                    o.z = f2bf_rne(v.z); o.w = f2bf_rne(v.w);
                    *(ushort4*)&Cb[(size_t)row * BN + c * 64 + g * 4] = o;
                } else {
                    *(float4*)&C[(size_t)row * BN + c * 64 + g * 4] = v;
                }
            }
        }
    }
}

// ---------------- aggregation over bf16 gather table (ushort csr) ----------------
// Persistent waves, 16-edge batch ILP (R14/R15 proven plateau).

#define AGG_WAVES 12800
#define AGG_BLOCKS (AGG_WAVES / 4)

template<int F, bool RELU, bool BIAS>
__global__ void aggregate_bf16_kernel(const unsigned short* __restrict__ xb,
                                      float* __restrict__ out,
                                      const float* __restrict__ dis,
                                      const int* __restrict__ starts,
                                      const int* __restrict__ ends,
                                      const unsigned short* __restrict__ csr_src,
                                      const float* __restrict__ bias,
                                      int n) {
    int wid = (blockIdx.x * blockDim.x + threadIdx.x) >> 6;
    int lane = threadIdx.x & 63;
    constexpr int VPT = F / 64;

    for (int v = wid; v < n; v += AGG_WAVES) {
        float dv = dis[v];
        float acc[VPT];
        if constexpr (VPT == 2) {
            ushort2 sv = *(const ushort2*)&xb[(size_t)v * F + lane * 2];
            acc[0] = bf2f(sv.x) * dv * dv;
            acc[1] = bf2f(sv.y) * dv * dv;
        } else {
            acc[0] = bf2f(xb[(size_t)v * F + lane]) * dv * dv;
        }
        int s = starts[v], e = ends[v];
        int p = s;
        for (; p + 16 <= e; p += 16) {
            int u[16];
            #pragma unroll
            for (int q = 0; q < 16; q++) u[q] = csr_src[p + q];
            float w[16];
            #pragma unroll
            for (int q = 0; q < 16; q++) w[q] = dis[u[q]] * dv;
            if constexpr (VPT == 2) {
                ushort2 g[16];
                #pragma unroll
                for (int q = 0; q < 16; q++)
                    g[q] = *(const ushort2*)&xb[(size_t)u[q] * F + lane * 2];
                #pragma unroll
                for (int q = 0; q < 16; q++) {
                    acc[0] += bf2f(g[q].x) * w[q];
                    acc[1] += bf2f(g[q].y) * w[q];
                }
            } else {
                unsigned short g[16];
                #pragma unroll
                for (int q = 0; q < 16; q++)
                    g[q] = xb[(size_t)u[q] * F + lane];
                #pragma unroll
                for (int q = 0; q < 16; q++) acc[0] += bf2f(g[q]) * w[q];
            }
        }
        for (; p + 8 <= e; p += 8) {
            int u[8];
            #pragma unroll
            for (int q = 0; q < 8; q++) u[q] = csr_src[p + q];
            float w[8];
            #pragma unroll
            for (int q = 0; q < 8; q++) w[q] = dis[u[q]] * dv;
            if constexpr (VPT == 2) {
                ushort2 g[8];
                #pragma unroll
                for (int q = 0; q < 8; q++)
                    g[q] = *(const ushort2*)&xb[(size_t)u[q] * F + lane * 2];
                #pragma unroll
                for (int q = 0; q < 8; q++) {
                    acc[0] += bf2f(g[q].x) * w[q];
                    acc[1] += bf2f(g[q].y) * w[q];
                }
            } else {
                unsigned short g[8];
                #pragma unroll
                for (int q = 0; q < 8; q++)
                    g[q] = xb[(size_t)u[q] * F + lane];
                #pragma unroll
                for (int q = 0; q < 8; q++) acc[0] += bf2f(g[q]) * w[q];
            }
        }
        for (; p < e; p++) {
            int u = csr_src[p];
            float w = dis[u] * dv;
            if constexpr (VPT == 2) {
                ushort2 g = *(const ushort2*)&xb[(size_t)u * F + lane * 2];
                acc[0] += bf2f(g.x) * w;
                acc[1] += bf2f(g.y) * w;
            } else {
                acc[0] += bf2f(xb[(size_t)u * F + lane]) * w;
            }
        }
        float* o = &out[(size_t)v * F + lane * VPT];
        #pragma unroll
        for (int i = 0; i < VPT; i++) {
            float r = acc[i];
            if (BIAS) r += bias[lane * VPT + i];
            if (RELU) r = fmaxf(r, 0.f);
            o[i] = r;
        }
    }
}

// ---------------- edge dot products: 16 lanes per edge, 4 edges per wave ----------------

__global__ void dot_kernel(const float* __restrict__ h,
                           const int* __restrict__ pos, const int* __restrict__ neg,
                           float* __restrict__ out) {
    int gw = (blockIdx.x * blockDim.x + threadIdx.x) >> 6;
    int lane = threadIdx.x & 63;
    int sub = lane >> 4;          // edge within wave (0..3)
    int pl = lane & 15;           // float4 position within row
    int e = gw * 4 + sub;
    if (e >= E_POS + E_NEG) return;
    int i0, i1;
    if (e < E_POS) { i0 = pos[e]; i1 = pos[E_POS + e]; }
    else { int t = e - E_POS; i0 = neg[t]; i1 = neg[E_NEG + t]; }
    float4 a = *(const float4*)&h[(size_t)i0 * 64 + pl * 4];
    float4 b = *(const float4*)&h[(size_t)i1 * 64 + pl * 4];
    float v = a.x * b.x + a.y * b.y + a.z * b.z + a.w * b.w;
    v += __shfl_xor(v, 1, 64);
    v += __shfl_xor(v, 2, 64);
    v += __shfl_xor(v, 4, 64);
    v += __shfl_xor(v, 8, 64);
    if (pl == 0) out[e] = v;
}

// ---------------- launch ----------------

extern "C" void kernel_launch(void* const* d_in, const int* in_sizes, int n_in,
                              void* d_out, int out_size, void* d_ws, size_t ws_size,
                              hipStream_t stream) {
    const float* x  = (const float*)d_in[0];
    const int* tei  = (const int*)d_in[1];
    const int* pos  = (const int*)d_in[2];
    const int* neg  = (const int*)d_in[3];
    const float* W1 = (const float*)d_in[4];
    const float* b1 = (const float*)d_in[5];
    const float* W2 = (const float*)d_in[6];
    const float* b2 = (const float*)d_in[7];
    const float* W3 = (const float*)d_in[8];
    const float* b3 = (const float*)d_in[9];
    float* out = (float*)d_out;

    const int* src = tei;
    const int* dst = tei + E_TRAIN;

    char* ws = (char*)d_ws;
    size_t off = 0;
    auto alloc = [&](size_t bytes) -> void* {
        void* p = ws + off;
        off = (off + bytes + 255) & ~(size_t)255;
        return p;
    };
    unsigned short* xb   = (unsigned short*)alloc((size_t)N_NODES * 128 * 2);  // x bf16
    float* aggX          = (float*)alloc((size_t)N_NODES * 128 * 4);
    float* h1            = (float*)alloc((size_t)N_NODES * 256 * 4);
    unsigned short* xw2b = (unsigned short*)alloc((size_t)N_NODES * 128 * 2);
    float* h2            = (float*)alloc((size_t)N_NODES * 128 * 4);
    unsigned short* xw3b = (unsigned short*)alloc((size_t)N_NODES * 64 * 2);
    float* h3            = (float*)alloc((size_t)N_NODES * 64 * 4);
    float* dis  = (float*)alloc(N_NODES * 4);
    int* offs   = (int*)alloc(N_NODES * 4);
    int* ends   = (int*)alloc(N_NODES * 4);
    int* gcount = (int*)alloc(NBUCK * 4);
    int* gbase  = (int*)alloc(NBUCK * 4);
    unsigned int* temp  = (unsigned int*)alloc((size_t)NBUCK * BSTRIDE * 4);
    unsigned short* csr = (unsigned short*)alloc((size_t)E_TRAIN * 2);
    short* Wt1h = (short*)alloc((size_t)128 * 256 * 2);
    short* Wt1l = (short*)alloc((size_t)128 * 256 * 2);
    short* Wt2h = (short*)alloc((size_t)256 * 128 * 2);
    short* Wt2l = (short*)alloc((size_t)256 * 128 * 2);
    short* Wt3h = (short*)alloc((size_t)128 * 64 * 2);
    short* Wt3l = (short*)alloc((size_t)128 * 64 * 2);
    (void)ws_size; (void)n_in; (void)in_sizes; (void)out_size;

    // CSR build: memset(196 ints) + partA + scanb + partB
    hipMemsetAsync(gcount, 0, NBUCK * 4, stream);
    partA_kernel<<<(E_TRAIN + 4095) / 4096, 256, 0, stream>>>(src, dst, gcount, temp, E_TRAIN);
    scanb_kernel<<<1, 256, 0, stream>>>(gcount, gbase);
    partB_kernel<<<NBUCK, 256, 0, stream>>>(temp, gcount, gbase, dis, offs, ends, csr);

    const int n4 = N_NODES * 128 / 4;
    prep_kernel<<<(WTOT + n4 + 255) / 256, 256, 0, stream>>>(
        W1, Wt1h, Wt1l, W2, Wt2h, Wt2l, W3, Wt3h, Wt3l, x, xb, n4);

    const int GB = (N_NODES + 127) / 128;     // 391 blocks of 128 rows

    // layer 1 (agg-first): aggX = agg(xb) [F=128, fp32 out]; h1 = relu(aggX @ W1 + b1) [256 fp32]
    aggregate_bf16_kernel<128, false, false><<<AGG_BLOCKS, 256, 0, stream>>>(
        xb, aggX, dis, offs, ends, csr, nullptr, N_NODES);
    gemm_fulln_kernel<256, true, false><<<GB, 512, 0, stream>>>(
        aggX, Wt1h, Wt1l, b1, h1, nullptr, N_NODES, 128);

    // layer 2 (gemm-first): xw2 = h1 @ W2 [128, bf16 out]; h2 = relu(agg(xw2b) + b2) [fp32]
    gemm_fulln_kernel<128, false, true><<<GB, 512, 0, stream>>>(
        h1, Wt2h, Wt2l, nullptr, nullptr, xw2b, N_NODES, 256);
    aggregate_bf16_kernel<128, true, true><<<AGG_BLOCKS, 256, 0, stream>>>(
        xw2b, h2, dis, offs, ends, csr, b2, N_NODES);

    // layer 3 (gemm-first): xw3 = h2 @ W3 [64, bf16 out]; h3 = agg(xw3b) + b3 [fp32]
    gemm_fulln_kernel<64, false, true><<<GB, 512, 0, stream>>>(
        h2, Wt3h, Wt3l, nullptr, nullptr, xw3b, N_NODES, 128);
    aggregate_bf16_kernel<64, false, true><<<AGG_BLOCKS, 256, 0, stream>>>(
        xw3b, h3, dis, offs, ends, csr, b3, N_NODES);

    // edge dots over h3 (64 features, fp32): 4 edges per wave
    const int DOT_WAVES = (E_POS + E_NEG + 3) / 4;            // 100000 waves
    dot_kernel<<<(DOT_WAVES + 3) / 4, 256, 0, stream>>>(h3, pos, neg, out);
}

// Round 17
// 295.597 us; speedup vs baseline: 1.2787x; 1.1181x over previous
//
#include <hip/hip_runtime.h>
#include <math.h>

#define N_NODES 50000
#define E_TRAIN 800000
#define E_POS 200000
#define E_NEG 200000

#define NBUCK 196        // ceil(N_NODES/256) coarse dst-buckets
#define BSTRIDE 5120     // temp slots per bucket (mean 4082, 16 sigma margin)
#define PSTRIDE 9216     // padded csr slots per bucket (raw<=~4700 + 256*15 pad)
#define PARTA_BLOCKS 196 // ceil(E_TRAIN/4096)

// ---------------- bf16 helpers ----------------

__device__ inline void split_bf16(float f, short& h, short& l) {
    unsigned u = __float_as_uint(f);
    h = (short)(u >> 16);
    float rem = f - __uint_as_float(u & 0xFFFF0000u);
    l = (short)(__float_as_uint(rem) >> 16);
}

__device__ inline unsigned short f2bf_rne(float f) {
    unsigned u = __float_as_uint(f);
    unsigned r = u + 0x7FFFu + ((u >> 16) & 1u);
    return (unsigned short)(r >> 16);
}

__device__ inline float bf2f(unsigned short h) {
    return __uint_as_float(((unsigned)h) << 16);
}

#define WTOT (128 * 256 + 256 * 128 + 128 * 64)

// ---------------- merged: CSR partition phase A + weight/x prep ----------------
// blocks [0,196): partition edges into coarse buckets by dst>>8 (LDS histogram,
// one global atomic per (block,bucket), packed (src<<8|dst&255) runs into temp).
// blocks [196,...): weights -> transposed hi/lo bf16 + x -> bf16 table.

__global__ void partA_prep_kernel(
        const int* __restrict__ src, const int* __restrict__ dst,
        int* __restrict__ gcount, unsigned int* __restrict__ temp, int e,
        const float* __restrict__ W1, short* __restrict__ W1h, short* __restrict__ W1l,
        const float* __restrict__ W2, short* __restrict__ W2h, short* __restrict__ W2l,
        const float* __restrict__ W3, short* __restrict__ W3h, short* __restrict__ W3l,
        const float* __restrict__ x, unsigned short* __restrict__ xb, int n4) {
    __shared__ int hist[NBUCK];
    __shared__ int base[NBUCK];
    __shared__ int lcur[NBUCK];
    int tid = threadIdx.x;
    if (blockIdx.x < PARTA_BLOCKS) {
        for (int i = tid; i < NBUCK; i += 256) hist[i] = 0;
        __syncthreads();
        int start = blockIdx.x * 4096;
        int stop = min(start + 4096, e);
        for (int i = start + tid; i < stop; i += 256)
            atomicAdd(&hist[dst[i] >> 8], 1);
        __syncthreads();
        for (int i = tid; i < NBUCK; i += 256) {
            base[i] = atomicAdd(&gcount[i], hist[i]);
            lcur[i] = 0;
        }
        __syncthreads();
        for (int i = start + tid; i < stop; i += 256) {
            int d = dst[i];
            int b = d >> 8;
            int off = atomicAdd(&lcur[b], 1);
            temp[(size_t)b * BSTRIDE + base[b] + off] = ((unsigned)src[i] << 8) | (unsigned)(d & 255);
        }
    } else {
        int i = (blockIdx.x - PARTA_BLOCKS) * 256 + tid;
        if (i < WTOT) {
            const float* W; short *Wh, *Wl; int K, N;
            if (i < 128 * 256) { W = W1; Wh = W1h; Wl = W1l; K = 128; N = 256; }
            else if (i < 128 * 256 + 256 * 128) { i -= 128 * 256; W = W2; Wh = W2h; Wl = W2l; K = 256; N = 128; }
            else { i -= 128 * 256 + 256 * 128; W = W3; Wh = W3h; Wl = W3l; K = 128; N = 64; }
            int k = i / N, n = i - k * N;
            short h, l;
            split_bf16(W[i], h, l);
            Wh[(size_t)n * K + k] = h;
            Wl[(size_t)n * K + k] = l;
        } else {
            int j = i - WTOT;
            if (j < n4) {
                float4 v = ((const float4*)x)[j];
                ushort4 o;
                o.x = f2bf_rne(v.x); o.y = f2bf_rne(v.y);
                o.z = f2bf_rne(v.z); o.w = f2bf_rne(v.w);
                ((ushort4*)xb)[j] = o;
            }
        }
    }
}

// ---------------- phase B: per-bucket CSR with 16-padded node segments ----------------
// One block per bucket (256 nodes). Per-node counts -> dis/offs/ends (ends = padded
// end); edges placed via LDS cursors into bucket-local fixed-stride region; padding
// slots get sentinel 0xFFFF (converted to src=0/w=0 by wdis_kernel).

__global__ void partB_kernel(const unsigned int* __restrict__ temp,
                             const int* __restrict__ gcount,
                             float* __restrict__ dis, int* __restrict__ offs, int* __restrict__ ends,
                             unsigned short* __restrict__ csr) {
    __shared__ int cnt[256];
    __shared__ int loc[256];
    __shared__ int cursor[256];
    int b = blockIdx.x;
    int t = threadIdx.x;
    int total = gcount[b];
    size_t tbase = (size_t)b * BSTRIDE;
    cnt[t] = 0;
    __syncthreads();
    for (int i = t; i < total; i += 256)
        atomicAdd(&cnt[temp[tbase + i] & 255], 1);
    __syncthreads();
    int c = cnt[t];
    int pc = (c + 15) & ~15;           // padded count
    loc[t] = pc;
    __syncthreads();
    for (int d = 1; d < 256; d <<= 1) {
        int u = 0;
        if (t >= d) u = loc[t - d];
        __syncthreads();
        if (t >= d) loc[t] += u;
        __syncthreads();
    }
    int excl = loc[t] - pc;
    int node = b * 256 + t;
    int gstart = b * PSTRIDE + excl;   // 16-aligned (excl is sum of multiples of 16)
    if (node < N_NODES) {
        dis[node] = 1.0f / sqrtf((float)(c + 1));  // +1 self loop
        offs[node] = gstart;
        ends[node] = gstart + pc;      // padded end: agg loop is branch-free 16-batches
    }
    cursor[t] = gstart;
    __syncthreads();
    for (int i = t; i < total; i += 256) {
        unsigned v = temp[tbase + i];
        int pos = atomicAdd(&cursor[v & 255], 1);
        csr[pos] = (unsigned short)(v >> 8);
    }
    __syncthreads();
    for (int j = c; j < pc; j++)       // sentinel-fill own node's padding
        csr[gstart + j] = 0xFFFFu;
}

// edge weights: wdis[p] = dis[csr[p]] (fp32); sentinel -> src 0, weight 0.
__global__ void wdis_kernel(unsigned short* __restrict__ csr,
                            const float* __restrict__ dis,
                            float* __restrict__ wdis, int n) {
    int i = blockIdx.x * blockDim.x + threadIdx.x;
    if (i < n) {
        unsigned short s = csr[i];
        if (s == 0xFFFFu) { csr[i] = 0; wdis[i] = 0.f; }
        else wdis[i] = dis[s];
    }
}

// ---------------- MFMA GEMM: 512 threads, 128 rows x full N, A streamed, B in LDS ----------------
// (R11 structure, proven.) OBF: emit C as bf16 RNE for gather consumers; else fp32.

typedef short bf16x8 __attribute__((ext_vector_type(8)));
typedef float f32x4 __attribute__((ext_vector_type(4)));

template<int BN, bool BR, bool OBF>
__global__ __launch_bounds__(512) void gemm_fulln_kernel(
        const float* __restrict__ A,
        const short* __restrict__ Bth, const short* __restrict__ Btl,
        const float* __restrict__ bias, float* __restrict__ C,
        unsigned short* __restrict__ Cb,
        int M, int K) {
    constexpr int NI = BN / 16;
    constexpr int BCH = BN * 4;
    constexpr int BP = (BCH + 511) / 512;
    constexpr size_t BSZ = (size_t)2 * BN * 40 * 2;
    constexpr size_t TSZ = (size_t)8 * 16 * 68 * 4;
    __shared__ __align__(16) char smem[BSZ > TSZ ? BSZ : TSZ];
    short* Bhi = (short*)smem;
    short* Blo = (short*)(smem + (size_t)BN * 40 * 2);
    float* tr  = (float*)smem;

    int tid = threadIdx.x;
    int lane = tid & 63;
    int wv = tid >> 6;
    int brow = blockIdx.x * 128;
    int m_lane = lane & 15;
    int kgrp = lane >> 4;

    int myrow = brow + wv * 16 + m_lane;
    if (myrow >= M) myrow = M - 1;
    const float* Ap = &A[(size_t)myrow * K + kgrp * 8];

    f32x4 acc[NI];
    #pragma unroll
    for (int i = 0; i < NI; i++) acc[i] = (f32x4){0.f, 0.f, 0.f, 0.f};

    int4 bhReg[BP], blReg[BP];
    float4 aN0, aN1, aC0, aC1;

    auto loadB = [&](int k0) {
        #pragma unroll
        for (int p = 0; p < BP; p++) {
            int idx = p * 512 + tid;
            if (idx < BCH) {
                int col = idx >> 2;
                int kc = idx & 3;
                size_t o = (size_t)col * K + k0 + kc * 8;
                bhReg[p] = *(const int4*)&Bth[o];
                blReg[p] = *(const int4*)&Btl[o];
            }
        }
    };
    auto loadA = [&](int k0) {
        aN0 = *(const float4*)&Ap[k0];
        aN1 = *(const float4*)&Ap[k0 + 4];
    };

    loadB(0); loadA(0);

    for (int k0 = 0; k0 < K; k0 += 32) {
        aC0 = aN0; aC1 = aN1;
        #pragma unroll
        for (int p = 0; p < BP; p++) {
            int idx = p * 512 + tid;
            if (idx < BCH) {
                int col = idx >> 2;
                int kc = idx & 3;
                *(int4*)&Bhi[col * 40 + kc * 8] = bhReg[p];
                *(int4*)&Blo[col * 40 + kc * 8] = blReg[p];
            }
        }
        __syncthreads();

        if (k0 + 32 < K) { loadB(k0 + 32); loadA(k0 + 32); }

        bf16x8 ah, al;
        {
            short h, l;
            split_bf16(aC0.x, h, l); ah[0] = h; al[0] = l;
            split_bf16(aC0.y, h, l); ah[1] = h; al[1] = l;
            split_bf16(aC0.z, h, l); ah[2] = h; al[2] = l;
            split_bf16(aC0.w, h, l); ah[3] = h; al[3] = l;
            split_bf16(aC1.x, h, l); ah[4] = h; al[4] = l;
            split_bf16(aC1.y, h, l); ah[5] = h; al[5] = l;
            split_bf16(aC1.z, h, l); ah[6] = h; al[6] = l;
            split_bf16(aC1.w, h, l); ah[7] = h; al[7] = l;
        }
        #pragma unroll
        for (int ni = 0; ni < NI; ni++) {
            int boff = (ni * 16 + m_lane) * 40 + kgrp * 8;
            bf16x8 bh = *(const bf16x8*)&Bhi[boff];
            bf16x8 bl = *(const bf16x8*)&Blo[boff];
            acc[ni] = __builtin_amdgcn_mfma_f32_16x16x32_bf16(ah, bh, acc[ni], 0, 0, 0);
            acc[ni] = __builtin_amdgcn_mfma_f32_16x16x32_bf16(al, bh, acc[ni], 0, 0, 0);
            acc[ni] = __builtin_amdgcn_mfma_f32_16x16x32_bf16(ah, bl, acc[ni], 0, 0, 0);
        }
        __syncthreads();
    }

    #pragma unroll
    for (int c = 0; c < NI / 4; c++) {
        #pragma unroll
        for (int q = 0; q < 4; q++) {
            int ni = c * 4 + q;
            float bb = 0.f;
            if (BR) bb = bias[ni * 16 + m_lane];
            #pragma unroll
            for (int reg = 0; reg < 4; reg++) {
                float v = acc[ni][reg];
                if (BR) v = fmaxf(v + bb, 0.f);
                tr[wv * 1088 + (kgrp * 4 + reg) * 68 + q * 16 + m_lane] = v;
            }
        }
        #pragma unroll
        for (int j = 0; j < 4; j++) {
            int r = (lane >> 4) + j * 4;
            int g = lane & 15;
            float4 v = *(const float4*)&tr[wv * 1088 + r * 68 + g * 4];
            int row = brow + wv * 16 + r;
            if (row < M) {
                if (OBF) {
                    ushort4 o;
                    o.x = f2bf_rne(v.x); o.y = f2bf_rne(v.y);
                    o.z = f2bf_rne(v.z); o.w = f2bf_rne(v.w);
                    *(ushort4*)&Cb[(size_t)row * BN + c * 64 + g * 4] = o;
                } else {
                    *(float4*)&C[(size_t)row * BN + c * 64 + g * 4] = v;
                }
            }
        }
    }
}

// ---------------- aggregation: bf16 table, padded CSR, precomputed edge weights ----
// Per 16-edge batch: 2 int4 (csr) + 4 float4 (wdis) wave-uniform aligned loads +
// 16 feature gathers. Branch-free (segments padded; pad entries src=0, w=0).

#define AGG_WAVES 12800
#define AGG_BLOCKS (AGG_WAVES / 4)

template<int F, bool RELU, bool BIAS>
__global__ void aggregate_bf16_kernel(const unsigned short* __restrict__ xb,
                                      float* __restrict__ out,
                                      const float* __restrict__ dis,
                                      const int* __restrict__ starts,
                                      const int* __restrict__ ends,
                                      const unsigned short* __restrict__ csr_src,
                                      const float* __restrict__ wdis,
                                      const float* __restrict__ bias,
                                      int n) {
    int wid = (blockIdx.x * blockDim.x + threadIdx.x) >> 6;
    int lane = threadIdx.x & 63;
    constexpr int VPT = F / 64;

    for (int v = wid; v < n; v += AGG_WAVES) {
        float dv = dis[v];
        float acc[VPT];
        if constexpr (VPT == 2) {
            ushort2 sv = *(const ushort2*)&xb[(size_t)v * F + lane * 2];
            acc[0] = bf2f(sv.x) * dv * dv;
            acc[1] = bf2f(sv.y) * dv * dv;
        } else {
            acc[0] = bf2f(xb[(size_t)v * F + lane]) * dv * dv;
        }
        int s = __builtin_amdgcn_readfirstlane(starts[v]);
        int e = __builtin_amdgcn_readfirstlane(ends[v]);
        for (int p = s; p < e; p += 16) {
            int4 c0 = *(const int4*)&csr_src[p];       // 8 ushorts (32B, 16-aligned)
            int4 c1 = *(const int4*)&csr_src[p + 8];
            float4 w0 = *(const float4*)&wdis[p];
            float4 w1 = *(const float4*)&wdis[p + 4];
            float4 w2 = *(const float4*)&wdis[p + 8];
            float4 w3 = *(const float4*)&wdis[p + 12];
            int u[16];
            u[0] = (unsigned)c0.x & 0xFFFF; u[1] = (unsigned)c0.x >> 16;
            u[2] = (unsigned)c0.y & 0xFFFF; u[3] = (unsigned)c0.y >> 16;
            u[4] = (unsigned)c0.z & 0xFFFF; u[5] = (unsigned)c0.z >> 16;
            u[6] = (unsigned)c0.w & 0xFFFF; u[7] = (unsigned)c0.w >> 16;
            u[8] = (unsigned)c1.x & 0xFFFF; u[9] = (unsigned)c1.x >> 16;
            u[10] = (unsigned)c1.y & 0xFFFF; u[11] = (unsigned)c1.y >> 16;
            u[12] = (unsigned)c1.z & 0xFFFF; u[13] = (unsigned)c1.z >> 16;
            u[14] = (unsigned)c1.w & 0xFFFF; u[15] = (unsigned)c1.w >> 16;
            float w[16];
            w[0] = w0.x * dv; w[1] = w0.y * dv; w[2] = w0.z * dv; w[3] = w0.w * dv;
            w[4] = w1.x * dv; w[5] = w1.y * dv; w[6] = w1.z * dv; w[7] = w1.w * dv;
            w[8] = w2.x * dv; w[9] = w2.y * dv; w[10] = w2.z * dv; w[11] = w2.w * dv;
            w[12] = w3.x * dv; w[13] = w3.y * dv; w[14] = w3.z * dv; w[15] = w3.w * dv;
            if constexpr (VPT == 2) {
                ushort2 g[16];
                #pragma unroll
                for (int q = 0; q < 16; q++)
                    g[q] = *(const ushort2*)&xb[(size_t)u[q] * F + lane * 2];
                #pragma unroll
                for (int q = 0; q < 16; q++) {
                    acc[0] += bf2f(g[q].x) * w[q];
                    acc[1] += bf2f(g[q].y) * w[q];
                }
            } else {
                unsigned short g[16];
                #pragma unroll
                for (int q = 0; q < 16; q++)
                    g[q] = xb[(size_t)u[q] * F + lane];
                #pragma unroll
                for (int q = 0; q < 16; q++) acc[0] += bf2f(g[q]) * w[q];
            }
        }
        float* o = &out[(size_t)v * F + lane * VPT];
        #pragma unroll
        for (int i = 0; i < VPT; i++) {
            float r = acc[i];
            if (BIAS) r += bias[lane * VPT + i];
            if (RELU) r = fmaxf(r, 0.f);
            o[i] = r;
        }
    }
}

// ---------------- edge dot products: 16 lanes per edge, 4 edges per wave ----------------

__global__ void dot_kernel(const float* __restrict__ h,
                           const int* __restrict__ pos, const int* __restrict__ neg,
                           float* __restrict__ out) {
    int gw = (blockIdx.x * blockDim.x + threadIdx.x) >> 6;
    int lane = threadIdx.x & 63;
    int sub = lane >> 4;
    int pl = lane & 15;
    int e = gw * 4 + sub;
    if (e >= E_POS + E_NEG) return;
    int i0, i1;
    if (e < E_POS) { i0 = pos[e]; i1 = pos[E_POS + e]; }
    else { int t = e - E_POS; i0 = neg[t]; i1 = neg[E_NEG + t]; }
    float4 a = *(const float4*)&h[(size_t)i0 * 64 + pl * 4];
    float4 b = *(const float4*)&h[(size_t)i1 * 64 + pl * 4];
    float v = a.x * b.x + a.y * b.y + a.z * b.z + a.w * b.w;
    v += __shfl_xor(v, 1, 64);
    v += __shfl_xor(v, 2, 64);
    v += __shfl_xor(v, 4, 64);
    v += __shfl_xor(v, 8, 64);
    if (pl == 0) out[e] = v;
}

// ---------------- launch ----------------

extern "C" void kernel_launch(void* const* d_in, const int* in_sizes, int n_in,
                              void* d_out, int out_size, void* d_ws, size_t ws_size,
                              hipStream_t stream) {
    const float* x  = (const float*)d_in[0];
    const int* tei  = (const int*)d_in[1];
    const int* pos  = (const int*)d_in[2];
    const int* neg  = (const int*)d_in[3];
    const float* W1 = (const float*)d_in[4];
    const float* b1 = (const float*)d_in[5];
    const float* W2 = (const float*)d_in[6];
    const float* b2 = (const float*)d_in[7];
    const float* W3 = (const float*)d_in[8];
    const float* b3 = (const float*)d_in[9];
    float* out = (float*)d_out;

    const int* src = tei;
    const int* dst = tei + E_TRAIN;

    char* ws = (char*)d_ws;
    size_t off = 0;
    auto alloc = [&](size_t bytes) -> void* {
        void* p = ws + off;
        off = (off + bytes + 255) & ~(size_t)255;
        return p;
    };
    unsigned short* xb   = (unsigned short*)alloc((size_t)N_NODES * 128 * 2);
    float* aggX          = (float*)alloc((size_t)N_NODES * 128 * 4);
    float* h1            = (float*)alloc((size_t)N_NODES * 256 * 4);
    unsigned short* xw2b = (unsigned short*)alloc((size_t)N_NODES * 128 * 2);
    float* h2            = (float*)alloc((size_t)N_NODES * 128 * 4);
    unsigned short* xw3b = (unsigned short*)alloc((size_t)N_NODES * 64 * 2);
    float* h3            = (float*)alloc((size_t)N_NODES * 64 * 4);
    float* dis  = (float*)alloc(N_NODES * 4);
    int* offs   = (int*)alloc(N_NODES * 4);
    int* ends   = (int*)alloc(N_NODES * 4);
    int* gcount = (int*)alloc(NBUCK * 4);
    unsigned int* temp  = (unsigned int*)alloc((size_t)NBUCK * BSTRIDE * 4);
    unsigned short* csr = (unsigned short*)alloc((size_t)NBUCK * PSTRIDE * 2);
    float* wdis         = (float*)alloc((size_t)NBUCK * PSTRIDE * 4);
    short* Wt1h = (short*)alloc((size_t)128 * 256 * 2);
    short* Wt1l = (short*)alloc((size_t)128 * 256 * 2);
    short* Wt2h = (short*)alloc((size_t)256 * 128 * 2);
    short* Wt2l = (short*)alloc((size_t)256 * 128 * 2);
    short* Wt3h = (short*)alloc((size_t)128 * 64 * 2);
    short* Wt3l = (short*)alloc((size_t)128 * 64 * 2);
    (void)ws_size; (void)n_in; (void)in_sizes; (void)out_size;

    const int n4 = N_NODES * 128 / 4;

    // CSR build + prep (fused): memset + partA/prep + partB + wdis
    hipMemsetAsync(gcount, 0, NBUCK * 4, stream);
    {
        int prep_blocks = (WTOT + n4 + 255) / 256;
        partA_prep_kernel<<<PARTA_BLOCKS + prep_blocks, 256, 0, stream>>>(
            src, dst, gcount, temp, E_TRAIN,
            W1, Wt1h, Wt1l, W2, Wt2h, Wt2l, W3, Wt3h, Wt3l, x, xb, n4);
    }
    partB_kernel<<<NBUCK, 256, 0, stream>>>(temp, gcount, dis, offs, ends, csr);
    {
        int ncsr = NBUCK * PSTRIDE;
        wdis_kernel<<<(ncsr + 255) / 256, 256, 0, stream>>>(csr, dis, wdis, ncsr);
    }

    const int GB = (N_NODES + 127) / 128;

    // layer 1 (agg-first): aggX = agg(xb); h1 = relu(aggX @ W1 + b1)
    aggregate_bf16_kernel<128, false, false><<<AGG_BLOCKS, 256, 0, stream>>>(
        xb, aggX, dis, offs, ends, csr, wdis, nullptr, N_NODES);
    gemm_fulln_kernel<256, true, false><<<GB, 512, 0, stream>>>(
        aggX, Wt1h, Wt1l, b1, h1, nullptr, N_NODES, 128);

    // layer 2 (gemm-first): xw2 = h1 @ W2 (bf16 out); h2 = relu(agg + b2)
    gemm_fulln_kernel<128, false, true><<<GB, 512, 0, stream>>>(
        h1, Wt2h, Wt2l, nullptr, nullptr, xw2b, N_NODES, 256);
    aggregate_bf16_kernel<128, true, true><<<AGG_BLOCKS, 256, 0, stream>>>(
        xw2b, h2, dis, offs, ends, csr, wdis, b2, N_NODES);

    // layer 3 (gemm-first): xw3 = h2 @ W3 (bf16 out); h3 = agg + b3
    gemm_fulln_kernel<64, false, true><<<GB, 512, 0, stream>>>(
        h2, Wt3h, Wt3l, nullptr, nullptr, xw3b, N_NODES, 128);
    aggregate_bf16_kernel<64, false, true><<<AGG_BLOCKS, 256, 0, stream>>>(
        xw3b, h3, dis, offs, ends, csr, wdis, b3, N_NODES);

    // edge dots over h3 (64 features, fp32): 4 edges per wave
    const int DOT_WAVES = (E_POS + E_NEG + 3) / 4;
    dot_kernel<<<(DOT_WAVES + 3) / 4, 256, 0, stream>>>(h3, pos, neg, out);
}